// Round 8
// baseline (164.765 us; speedup 1.0000x reference)
//
#include <hip/hip_runtime.h>

// KnowledgeEmbedding loss via bf16 MFMA GEMMs.
// Per relation r: score(row,neg) = dot(head[h_row]+rvec_r, tail[neg]) + bias[t_row]
// loss = (1/B) * sum_rel [ sum_row softplus(-pos_row) + sum_{row,neg} softplus(score) ]
//
// Block = 64 rows x 128 negs, K=100 padded to 128 (4 MFMA k-steps, 16x16x32 bf16).
// Bias folded into GEMM (A[k=100]=bias, B[k=100]=1.0) -> epilogue is a pure
// layout-agnostic softplus-sum. LDS 48 KB -> 3 blocks/CU (R7's 128x128 tile was
// 64 KB -> 2/CU with grid 512 = no replacement pipeline; this is the occupancy fix).
// Staging: t<64 stages A row t (head+rvec, bf16 RNE); t in [64,192) stages B row;
// t>=192 idles at stage and, in nb==0 blocks, computes the positive term with
// ex decoded from LDS (saves the 13 MB head re-gather of R7).
// HISTORY: R1-R6 VALU GEMM plateaued 43.5 us (gather-path bound). R7 MFMA: ~30 us.

#define EMBED   100
#define BATCH   4096
#define NUM_NEG 256
#define BM      64
#define BN      128
#define PITCH   128   // shorts per LDS row (256 B)

typedef __attribute__((ext_vector_type(8))) short s8;
typedef __attribute__((ext_vector_type(4))) short s4;
typedef __attribute__((ext_vector_type(4))) float f4;

struct RelP {
    const float* head;
    const float* tail;
    const float* bias;
    int hc, tc;
};

struct Params {
    RelP rel[8];
    const float* rel_vecs;
    const int*   batch_idxs;
    const int*   neg_idxs;
    float*       out;
};

__device__ __forceinline__ float softplus_f(float x) {
    float e = __expf(-fabsf(x));
    return fmaxf(x, 0.0f) + __logf(1.0f + e);
}

__device__ __forceinline__ unsigned short bf16_rne(float f) {
    unsigned u = __float_as_uint(f);
    u += 0x7FFFu + ((u >> 16) & 1u);
    return (unsigned short)(u >> 16);
}

__device__ __forceinline__ float bf16_to_f(short s) {
    return __uint_as_float(((unsigned)(unsigned short)s) << 16);
}

__launch_bounds__(256, 3)
__global__ void ke_kernel(Params p) {
    // grid: 8 rel * 64 rowblocks * 2 negblocks = 1024
    const int bid = blockIdx.x;
    const int r   = bid & 7;
    const int rb  = (bid >> 3) & 63;
    const int nb  = bid >> 9;            // 0..1
    const int tid = threadIdx.x;

    __shared__ __align__(16) short As[BM * PITCH];   // [row][k] bf16, k100=bias
    __shared__ __align__(16) short Bs[BN * PITCH];   // [neg][k] bf16, k100=1.0

    const RelP rp = p.rel[r];

    // ---- staging: t<64 -> A row t; t in [64,192) -> B row t-64; else idle ----
    if (tid < 192) {
        const bool isA = tid < BM;
        const float* src;
        unsigned short extra;            // value at k=100
        short* dst;
        if (isA) {
            const int grow = rb * BM + tid;
            const int h  = p.batch_idxs[grow * 8 + rp.hc];
            const int ti = p.batch_idxs[grow * 8 + rp.tc];
            src   = rp.head + (size_t)h * EMBED;
            extra = bf16_rne(rp.bias[ti]);
            dst   = As + tid * PITCH;
        } else {
            const int n = p.neg_idxs[r * NUM_NEG + nb * BN + (tid - BM)];
            src   = rp.tail + (size_t)n * EMBED;
            extra = 0x3F80;              // bf16(1.0)
            dst   = Bs + (tid - BM) * PITCH;
        }
        const float4* s4p = (const float4*)src;
        const float4* rv4 = (const float4*)(p.rel_vecs + r * EMBED);

#pragma unroll
        for (int j = 0; j < 12; ++j) {
            float4 f0 = s4p[2 * j];
            float4 f1 = s4p[2 * j + 1];
            if (isA) {
                const float4 a = rv4[2 * j];
                const float4 b = rv4[2 * j + 1];
                f0.x += a.x; f0.y += a.y; f0.z += a.z; f0.w += a.w;
                f1.x += b.x; f1.y += b.y; f1.z += b.z; f1.w += b.w;
            }
            s8 v = { (short)bf16_rne(f0.x), (short)bf16_rne(f0.y),
                     (short)bf16_rne(f0.z), (short)bf16_rne(f0.w),
                     (short)bf16_rne(f1.x), (short)bf16_rne(f1.y),
                     (short)bf16_rne(f1.z), (short)bf16_rne(f1.w) };
            *(s8*)(dst + 8 * j) = v;
        }
        {   // floats 96..99
            float4 f = s4p[24];
            if (isA) {
                const float4 a = rv4[24];
                f.x += a.x; f.y += a.y; f.z += a.z; f.w += a.w;
            }
            s4 v = { (short)bf16_rne(f.x), (short)bf16_rne(f.y),
                     (short)bf16_rne(f.z), (short)bf16_rne(f.w) };
            *(s4*)(dst + 96) = v;
        }
        {   // k=100 (bias / 1.0), zeros k=101..127
            s4 v = { (short)extra, 0, 0, 0 };
            *(s4*)(dst + 100) = v;
            s4 z = { 0, 0, 0, 0 };
#pragma unroll
            for (int j = 0; j < 6; ++j)
                *(s4*)(dst + 104 + 4 * j) = z;
        }
    }

    // pos-term address prep for threads 192..255 (loads issued before barrier)
    const bool doPos = (nb == 0) && (tid >= 192);
    const int  prow  = rb * BM + (tid - 192);              // valid only if doPos
    int   pt   = 0;
    const float* ptail = rp.tail;
    float pbias = 0.0f;
    if (doPos) {
        pt    = p.batch_idxs[prow * 8 + rp.tc];
        ptail = rp.tail + (size_t)pt * EMBED;
        pbias = rp.bias[pt];
    }

    __syncthreads();

    // ---- MFMA compute: 4 waves, wave tile 32 rows x 64 negs ----
    const int wave = tid >> 6;
    const int lane = tid & 63;
    const int li   = lane & 15;
    const int q    = lane >> 4;
    const int wm   = wave & 1;           // row half (32)
    const int wn   = wave >> 1;          // neg half (64)

    f4 acc[2][4];
#pragma unroll
    for (int i = 0; i < 2; ++i)
#pragma unroll
        for (int j = 0; j < 4; ++j)
            acc[i][j] = (f4){0.f, 0.f, 0.f, 0.f};

    const short* Abase = As + (wm * 32 + li) * PITCH + q * 8;
    const short* Bbase = Bs + (wn * 64 + li) * PITCH + q * 8;

#pragma unroll
    for (int s = 0; s < 4; ++s) {
        const s8 a0 = *(const s8*)(Abase +  0 * PITCH + s * 32);
        const s8 a1 = *(const s8*)(Abase + 16 * PITCH + s * 32);
        const s8 b0 = *(const s8*)(Bbase +  0 * PITCH + s * 32);
        const s8 b1 = *(const s8*)(Bbase + 16 * PITCH + s * 32);
        const s8 b2 = *(const s8*)(Bbase + 32 * PITCH + s * 32);
        const s8 b3 = *(const s8*)(Bbase + 48 * PITCH + s * 32);
        acc[0][0] = __builtin_amdgcn_mfma_f32_16x16x32_bf16(a0, b0, acc[0][0], 0, 0, 0);
        acc[0][1] = __builtin_amdgcn_mfma_f32_16x16x32_bf16(a0, b1, acc[0][1], 0, 0, 0);
        acc[0][2] = __builtin_amdgcn_mfma_f32_16x16x32_bf16(a0, b2, acc[0][2], 0, 0, 0);
        acc[0][3] = __builtin_amdgcn_mfma_f32_16x16x32_bf16(a0, b3, acc[0][3], 0, 0, 0);
        acc[1][0] = __builtin_amdgcn_mfma_f32_16x16x32_bf16(a1, b0, acc[1][0], 0, 0, 0);
        acc[1][1] = __builtin_amdgcn_mfma_f32_16x16x32_bf16(a1, b1, acc[1][1], 0, 0, 0);
        acc[1][2] = __builtin_amdgcn_mfma_f32_16x16x32_bf16(a1, b2, acc[1][2], 0, 0, 0);
        acc[1][3] = __builtin_amdgcn_mfma_f32_16x16x32_bf16(a1, b3, acc[1][3], 0, 0, 0);
    }

    // ---- epilogue: softplus-sum (bias already inside acc) ----
    float local = 0.0f;
#pragma unroll
    for (int i = 0; i < 2; ++i)
#pragma unroll
        for (int j = 0; j < 4; ++j) {
            local += softplus_f(acc[i][j].x);
            local += softplus_f(acc[i][j].y);
            local += softplus_f(acc[i][j].z);
            local += softplus_f(acc[i][j].w);
        }

    // ---- positive term on the 64 non-staging threads (nb==0 only) ----
    // ex comes from As (bf16) -> no head re-gather; tail gathered fp32.
    if (doPos) {
        const short* exr = As + (tid - 192) * PITCH;
        const float4* tv = (const float4*)ptail;
        float d0 = 0.f, d1 = 0.f, d2 = 0.f, d3 = 0.f;
#pragma unroll
        for (int j = 0; j < 25; ++j) {
            const s4 e = *(const s4*)(exr + 4 * j);
            const float4 v = tv[j];
            d0 = fmaf(bf16_to_f(e.x), v.x, d0);
            d1 = fmaf(bf16_to_f(e.y), v.y, d1);
            d2 = fmaf(bf16_to_f(e.z), v.z, d2);
            d3 = fmaf(bf16_to_f(e.w), v.w, d3);
        }
        const float pos = ((d0 + d1) + (d2 + d3)) + pbias;
        local += softplus_f(-pos);
    }

    // ---- reduction: wave shuffle, then LDS (aliased over Bs after barrier) ----
#pragma unroll
    for (int off = 32; off > 0; off >>= 1)
        local += __shfl_down(local, off, 64);

    __syncthreads();                     // all As/Bs reads done -> safe to alias
    float* wsum = (float*)Bs;
    if (lane == 0) wsum[wave] = local;
    __syncthreads();
    if (tid == 0) {
        const float s = (wsum[0] + wsum[1]) + (wsum[2] + wsum[3]);
        atomicAdd(p.out, s * (1.0f / BATCH));
    }
}

extern "C" void kernel_launch(void* const* d_in, const int* in_sizes, int n_in,
                              void* d_out, int out_size, void* d_ws, size_t ws_size,
                              hipStream_t stream) {
    const float* user  = (const float*)d_in[0];
    const float* prod  = (const float*)d_in[1];
    const float* word  = (const float*)d_in[2];
    const float* brand = (const float*)d_in[3];
    const float* cat   = (const float*)d_in[4];
    const float* rprod = (const float*)d_in[5];

    Params p;
    p.rel_vecs   = (const float*)d_in[6];
    p.batch_idxs = (const int*)d_in[15];
    p.neg_idxs   = (const int*)d_in[16];
    p.out        = (float*)d_out;

    p.rel[0] = {user, prod,  (const float*)d_in[7],  0, 1};  // purchase
    p.rel[1] = {user, word,  (const float*)d_in[8],  0, 2};  // mentions
    p.rel[2] = {prod, word,  (const float*)d_in[9],  1, 2};  // describe
    p.rel[3] = {prod, brand, (const float*)d_in[10], 1, 3};  // produced
    p.rel[4] = {prod, cat,   (const float*)d_in[11], 1, 4};  // belongs
    p.rel[5] = {prod, rprod, (const float*)d_in[12], 1, 5};  // also_bought
    p.rel[6] = {prod, rprod, (const float*)d_in[13], 1, 6};  // also_viewed
    p.rel[7] = {prod, rprod, (const float*)d_in[14], 1, 7};  // together

    hipMemsetAsync(d_out, 0, sizeof(float), stream);
    ke_kernel<<<1024, 256, 0, stream>>>(p);
}

// Round 9
// 162.369 us; speedup vs baseline: 1.0148x; 1.0148x over previous
//
#include <hip/hip_runtime.h>

// KnowledgeEmbedding loss via bf16 MFMA GEMMs.
// Per relation r: score(row,neg) = dot(head[h_row]+rvec_r, tail[neg]) + bias[t_row]
// loss = (1/B) * sum_rel [ sum_row softplus(-pos_row) + sum_{row,neg} softplus(score) ]
//
// Block = 64 rows x 128 negs, K=100 padded to 128 (4 MFMA k-steps, 16x16x32 bf16).
// Bias folded into GEMM (A[k=100]=bias, B[k=100]=1.0) -> epilogue is a pure
// layout-agnostic softplus-sum.
// PITCH = 136 shorts (272 B = 68 words == 4 mod 32 banks): fragment reads hit
// banks 4(li+q)%32 and staging writes 4(l+j)%32 -- both perfectly uniform
// (8 words/bank = minimum). PITCH=128 (R7/R8) put entire waves on 4 banks:
// SQ_LDS_BANK_CONFLICT 5.9M cyc, kernel 42 us. LDS 52.2 KB -> 3 blocks/CU.
// Staging: t<64 stages A row t (head+rvec, bf16 RNE); t in [64,192) B row;
// t>=192 computes the positive term (ex decoded from LDS, no head re-gather).
// HISTORY: R1-R6 VALU GEMM 43.5 us (gather-bound); R7 MFMA 128x128 ~30 us
// (conflicted); R8 64x128 3/CU 42 us (conflicts * 1.5x LDS traffic).

#define EMBED   100
#define BATCH   4096
#define NUM_NEG 256
#define BM      64
#define BN      128
#define PITCH   136   // shorts per LDS row (272 B; 68 words == 4 mod 32)

typedef __attribute__((ext_vector_type(8))) short s8;
typedef __attribute__((ext_vector_type(4))) short s4;
typedef __attribute__((ext_vector_type(4))) float f4;

struct RelP {
    const float* head;
    const float* tail;
    const float* bias;
    int hc, tc;
};

struct Params {
    RelP rel[8];
    const float* rel_vecs;
    const int*   batch_idxs;
    const int*   neg_idxs;
    float*       out;
};

__device__ __forceinline__ float softplus_f(float x) {
    float e = __expf(-fabsf(x));
    return fmaxf(x, 0.0f) + __logf(1.0f + e);
}

__device__ __forceinline__ unsigned short bf16_rne(float f) {
    unsigned u = __float_as_uint(f);
    u += 0x7FFFu + ((u >> 16) & 1u);
    return (unsigned short)(u >> 16);
}

__device__ __forceinline__ float bf16_to_f(short s) {
    return __uint_as_float(((unsigned)(unsigned short)s) << 16);
}

__launch_bounds__(256, 3)
__global__ void ke_kernel(Params p) {
    // grid: 8 rel * 64 rowblocks * 2 negblocks = 1024
    const int bid = blockIdx.x;
    const int r   = bid & 7;
    const int rb  = (bid >> 3) & 63;
    const int nb  = bid >> 9;            // 0..1
    const int tid = threadIdx.x;

    __shared__ __align__(16) short As[BM * PITCH];   // [row][k] bf16, k100=bias
    __shared__ __align__(16) short Bs[BN * PITCH];   // [neg][k] bf16, k100=1.0

    const RelP rp = p.rel[r];

    // ---- staging: t<64 -> A row t; t in [64,192) -> B row t-64; else pos ----
    if (tid < 192) {
        const bool isA = tid < BM;
        const float* src;
        unsigned short extra;            // value at k=100
        short* dst;
        if (isA) {
            const int grow = rb * BM + tid;
            const int h  = p.batch_idxs[grow * 8 + rp.hc];
            const int ti = p.batch_idxs[grow * 8 + rp.tc];
            src   = rp.head + (size_t)h * EMBED;
            extra = bf16_rne(rp.bias[ti]);
            dst   = As + tid * PITCH;
        } else {
            const int n = p.neg_idxs[r * NUM_NEG + nb * BN + (tid - BM)];
            src   = rp.tail + (size_t)n * EMBED;
            extra = 0x3F80;              // bf16(1.0)
            dst   = Bs + (tid - BM) * PITCH;
        }
        const float4* s4p = (const float4*)src;
        const float4* rv4 = (const float4*)(p.rel_vecs + r * EMBED);

#pragma unroll
        for (int j = 0; j < 12; ++j) {
            float4 f0 = s4p[2 * j];
            float4 f1 = s4p[2 * j + 1];
            if (isA) {
                const float4 a = rv4[2 * j];
                const float4 b = rv4[2 * j + 1];
                f0.x += a.x; f0.y += a.y; f0.z += a.z; f0.w += a.w;
                f1.x += b.x; f1.y += b.y; f1.z += b.z; f1.w += b.w;
            }
            s8 v = { (short)bf16_rne(f0.x), (short)bf16_rne(f0.y),
                     (short)bf16_rne(f0.z), (short)bf16_rne(f0.w),
                     (short)bf16_rne(f1.x), (short)bf16_rne(f1.y),
                     (short)bf16_rne(f1.z), (short)bf16_rne(f1.w) };
            *(s8*)(dst + 8 * j) = v;
        }
        {   // floats 96..99
            float4 f = s4p[24];
            if (isA) {
                const float4 a = rv4[24];
                f.x += a.x; f.y += a.y; f.z += a.z; f.w += a.w;
            }
            s4 v = { (short)bf16_rne(f.x), (short)bf16_rne(f.y),
                     (short)bf16_rne(f.z), (short)bf16_rne(f.w) };
            *(s4*)(dst + 96) = v;
        }
        {   // k=100 (bias / 1.0), zeros k=101..127
            s4 v = { (short)extra, 0, 0, 0 };
            *(s4*)(dst + 100) = v;
            s4 z = { 0, 0, 0, 0 };
#pragma unroll
            for (int j = 0; j < 6; ++j)
                *(s4*)(dst + 104 + 4 * j) = z;
        }
    }

    // pos-term address prep for threads 192..255 (loads issued before barrier)
    const bool doPos = (nb == 0) && (tid >= 192);
    const int  prow  = rb * BM + (tid - 192);              // valid only if doPos
    const float* ptail = rp.tail;
    float pbias = 0.0f;
    if (doPos) {
        const int pt = p.batch_idxs[prow * 8 + rp.tc];
        ptail = rp.tail + (size_t)pt * EMBED;
        pbias = rp.bias[pt];
    }

    __syncthreads();

    // ---- MFMA compute: 4 waves, wave tile 32 rows x 64 negs ----
    const int wave = tid >> 6;
    const int lane = tid & 63;
    const int li   = lane & 15;
    const int q    = lane >> 4;
    const int wm   = wave & 1;           // row half (32)
    const int wn   = wave >> 1;          // neg half (64)

    f4 acc[2][4];
#pragma unroll
    for (int i = 0; i < 2; ++i)
#pragma unroll
        for (int j = 0; j < 4; ++j)
            acc[i][j] = (f4){0.f, 0.f, 0.f, 0.f};

    const short* Abase = As + (wm * 32 + li) * PITCH + q * 8;
    const short* Bbase = Bs + (wn * 64 + li) * PITCH + q * 8;

#pragma unroll
    for (int s = 0; s < 4; ++s) {
        const s8 a0 = *(const s8*)(Abase +  0 * PITCH + s * 32);
        const s8 a1 = *(const s8*)(Abase + 16 * PITCH + s * 32);
        const s8 b0 = *(const s8*)(Bbase +  0 * PITCH + s * 32);
        const s8 b1 = *(const s8*)(Bbase + 16 * PITCH + s * 32);
        const s8 b2 = *(const s8*)(Bbase + 32 * PITCH + s * 32);
        const s8 b3 = *(const s8*)(Bbase + 48 * PITCH + s * 32);
        acc[0][0] = __builtin_amdgcn_mfma_f32_16x16x32_bf16(a0, b0, acc[0][0], 0, 0, 0);
        acc[0][1] = __builtin_amdgcn_mfma_f32_16x16x32_bf16(a0, b1, acc[0][1], 0, 0, 0);
        acc[0][2] = __builtin_amdgcn_mfma_f32_16x16x32_bf16(a0, b2, acc[0][2], 0, 0, 0);
        acc[0][3] = __builtin_amdgcn_mfma_f32_16x16x32_bf16(a0, b3, acc[0][3], 0, 0, 0);
        acc[1][0] = __builtin_amdgcn_mfma_f32_16x16x32_bf16(a1, b0, acc[1][0], 0, 0, 0);
        acc[1][1] = __builtin_amdgcn_mfma_f32_16x16x32_bf16(a1, b1, acc[1][1], 0, 0, 0);
        acc[1][2] = __builtin_amdgcn_mfma_f32_16x16x32_bf16(a1, b2, acc[1][2], 0, 0, 0);
        acc[1][3] = __builtin_amdgcn_mfma_f32_16x16x32_bf16(a1, b3, acc[1][3], 0, 0, 0);
    }

    // ---- epilogue: softplus-sum (bias already inside acc) ----
    float local = 0.0f;
#pragma unroll
    for (int i = 0; i < 2; ++i)
#pragma unroll
        for (int j = 0; j < 4; ++j) {
            local += softplus_f(acc[i][j].x);
            local += softplus_f(acc[i][j].y);
            local += softplus_f(acc[i][j].z);
            local += softplus_f(acc[i][j].w);
        }

    // ---- positive term on the 64 non-staging threads (nb==0 only) ----
    if (doPos) {
        const short* exr = As + (tid - 192) * PITCH;
        const float4* tv = (const float4*)ptail;
        float d0 = 0.f, d1 = 0.f, d2 = 0.f, d3 = 0.f;
#pragma unroll
        for (int j = 0; j < 25; ++j) {
            const s4 e = *(const s4*)(exr + 4 * j);
            const float4 v = tv[j];
            d0 = fmaf(bf16_to_f(e.x), v.x, d0);
            d1 = fmaf(bf16_to_f(e.y), v.y, d1);
            d2 = fmaf(bf16_to_f(e.z), v.z, d2);
            d3 = fmaf(bf16_to_f(e.w), v.w, d3);
        }
        const float pos = ((d0 + d1) + (d2 + d3)) + pbias;
        local += softplus_f(-pos);
    }

    // ---- reduction: wave shuffle, then LDS (aliased over Bs after barrier) ----
#pragma unroll
    for (int off = 32; off > 0; off >>= 1)
        local += __shfl_down(local, off, 64);

    __syncthreads();                     // all As/Bs reads done -> safe to alias
    float* wsum = (float*)Bs;
    if (lane == 0) wsum[wave] = local;
    __syncthreads();
    if (tid == 0) {
        const float s = (wsum[0] + wsum[1]) + (wsum[2] + wsum[3]);
        atomicAdd(p.out, s * (1.0f / BATCH));
    }
}

extern "C" void kernel_launch(void* const* d_in, const int* in_sizes, int n_in,
                              void* d_out, int out_size, void* d_ws, size_t ws_size,
                              hipStream_t stream) {
    const float* user  = (const float*)d_in[0];
    const float* prod  = (const float*)d_in[1];
    const float* word  = (const float*)d_in[2];
    const float* brand = (const float*)d_in[3];
    const float* cat   = (const float*)d_in[4];
    const float* rprod = (const float*)d_in[5];

    Params p;
    p.rel_vecs   = (const float*)d_in[6];
    p.batch_idxs = (const int*)d_in[15];
    p.neg_idxs   = (const int*)d_in[16];
    p.out        = (float*)d_out;

    p.rel[0] = {user, prod,  (const float*)d_in[7],  0, 1};  // purchase
    p.rel[1] = {user, word,  (const float*)d_in[8],  0, 2};  // mentions
    p.rel[2] = {prod, word,  (const float*)d_in[9],  1, 2};  // describe
    p.rel[3] = {prod, brand, (const float*)d_in[10], 1, 3};  // produced
    p.rel[4] = {prod, cat,   (const float*)d_in[11], 1, 4};  // belongs
    p.rel[5] = {prod, rprod, (const float*)d_in[12], 1, 5};  // also_bought
    p.rel[6] = {prod, rprod, (const float*)d_in[13], 1, 6};  // also_viewed
    p.rel[7] = {prod, rprod, (const float*)d_in[14], 1, 7};  // together

    hipMemsetAsync(d_out, 0, sizeof(float), stream);
    ke_kernel<<<1024, 256, 0, stream>>>(p);
}